// Round 1
// 528.714 us; speedup vs baseline: 1.0195x; 1.0195x over previous
//
#include <hip/hip_runtime.h>
#include <math.h>

// Problem constants (fixed by setup_inputs)
constexpr int B = 16, C = 64, H = 256, W = 256;
constexpr int HW = H * W;            // 65536
constexpr int BHW = B * HW;          // 1048576
constexpr int K = 11, P = 5;         // 11x11 gaussian, pad 5
#define EPS 1e-6f

// ---------------------------------------------------------------------------
// Kernel 1: channel reduction.  sxx = sum_c x^2, sxy = sum_c x*y, syy = sum_c y^2
// v2: C-loop split across two thread-halves (32 channels each) so the grid is
// 2048 blocks -> 8 blocks/CU -> 32 waves/CU (was 1024 -> 16 waves/CU, the
// occupancy cap that limited read concurrency to ~3.2 TB/s).
// Each thread owns 4 consecutive w-pixels (float4 loads, 16B/lane, fully
// coalesced: 64 lanes x 16B = 1 KB per instruction).
// ---------------------------------------------------------------------------
__global__ __launch_bounds__(256) void k_reduce(
    const float* __restrict__ x, const float* __restrict__ y,
    float* __restrict__ s /* [3][B][HW] */)
{
    const int GPI = HW / 4;                       // float4 groups per plane = 16384
    __shared__ float4 lds[3][128];

    int t = threadIdx.x;
    int half = t >> 7;                            // 0: c in [0,32), 1: c in [32,64)
    int lane = t & 127;
    int gidx = blockIdx.x * 128 + lane;           // [0, B*GPI)
    int b = gidx >> 14;                           // gidx / GPI
    int g = gidx & (GPI - 1);

    const float4* x4 = (const float4*)x + ((size_t)b * C + half * 32) * GPI + g;
    const float4* y4 = (const float4*)y + ((size_t)b * C + half * 32) * GPI + g;

    float4 axx = make_float4(0.f, 0.f, 0.f, 0.f);
    float4 axy = axx, ayy = axx;

#pragma unroll 8
    for (int c = 0; c < 32; ++c) {
        float4 xv = x4[c * GPI];
        float4 yv = y4[c * GPI];
        axx.x += xv.x * xv.x; axx.y += xv.y * xv.y;
        axx.z += xv.z * xv.z; axx.w += xv.w * xv.w;
        axy.x += xv.x * yv.x; axy.y += xv.y * yv.y;
        axy.z += xv.z * yv.z; axy.w += xv.w * yv.w;
        ayy.x += yv.x * yv.x; ayy.y += yv.y * yv.y;
        ayy.z += yv.z * yv.z; ayy.w += yv.w * yv.w;
    }

    if (half) {
        lds[0][lane] = axx;
        lds[1][lane] = axy;
        lds[2][lane] = ayy;
    }
    __syncthreads();
    if (!half) {
        float4 bxx = lds[0][lane], bxy = lds[1][lane], byy = lds[2][lane];
        axx.x += bxx.x; axx.y += bxx.y; axx.z += bxx.z; axx.w += bxx.w;
        axy.x += bxy.x; axy.y += bxy.y; axy.z += bxy.z; axy.w += bxy.w;
        ayy.x += byy.x; ayy.y += byy.y; ayy.z += byy.z; ayy.w += byy.w;

        float4* s4 = (float4*)s;
        s4[gidx]                  = axx;
        s4[(BHW / 4) + gidx]      = axy;
        s4[2 * (BHW / 4) + gidx]  = ayy;
    }
}

// ---------------------------------------------------------------------------
// Kernel 2: fused separable blur + cosine combine, one 32x32 output tile per
// block.  The 11x11 gaussian is rank-1: g2d[i][j] = (g[5][j]/sqrt(g[5][5])) *
// (g[i][5]/sqrt(g[5][5])).  Stage the 42x42 halo tile of all 3 maps in LDS
// (coalesced loads, L3-resident data), hblur into LDS, vblur+combine from LDS.
// Replaces two global-memory passes (and the 12 MB `t` round-trip) with one.
// LDS: 3*42*44*4 + 3*42*32*4 = 38.3 KB -> 4 blocks/CU.
// ---------------------------------------------------------------------------
constexpr int TH = 32, TW = 32;
constexpr int RH = TH + K - 1;   // 42 rows incl. halo
constexpr int RW = TW + K - 1;   // 42 cols incl. halo
constexpr int RWP = RW + 2;      // 44: pad row stride

__global__ __launch_bounds__(256) void k_blur_combine(
    const float* __restrict__ s, const float* __restrict__ gauss,
    float* __restrict__ out /* [B][HW] */)
{
    __shared__ float raw[3][RH][RWP];
    __shared__ float hb[3][RH][TW];

    int t = threadIdx.x;
    int blk = blockIdx.x;             // B * 8 * 8 = 1024
    int b  = blk >> 6;
    int th = (blk >> 3) & 7;
    int tw = blk & 7;
    int h0 = th * TH, w0 = tw * TW;

    // rank-1 weights (broadcast scalar loads, cached)
    float inv = 1.0f / sqrtf(gauss[5 * K + 5]);
    float wr[K], wc[K];
#pragma unroll
    for (int j = 0; j < K; ++j) wr[j] = gauss[5 * K + j] * inv;  // horizontal taps
#pragma unroll
    for (int i = 0; i < K; ++i) wc[i] = gauss[i * K + 5] * inv;  // vertical taps

    // stage raw 42x42 tiles of the 3 maps (zero-padded SAME)
    for (int m = 0; m < 3; ++m) {
        const float* sp = s + m * BHW + b * HW;
        for (int i = t; i < RH * RW; i += 256) {
            int r = i / RW;
            int c2 = i - r * RW;
            int h = h0 - P + r;
            int w = w0 - P + c2;
            float v = 0.f;
            if (h >= 0 && h < H && w >= 0 && w < W) v = sp[h * W + w];
            raw[m][r][c2] = v;
        }
    }
    __syncthreads();

    // horizontal blur: [3][42][32]
    for (int i = t; i < 3 * RH * TW; i += 256) {
        int m = i / (RH * TW);
        int rem = i - m * (RH * TW);
        int r = rem >> 5;            // / TW
        int cc = rem & (TW - 1);
        float a = 0.f;
#pragma unroll
        for (int j = 0; j < K; ++j) a += wr[j] * raw[m][r][cc + j];
        hb[m][r][cc] = a;
    }
    __syncthreads();

    // vertical blur + cosine combine: 32x32 outputs, 4 per thread
#pragma unroll
    for (int k = 0; k < 4; ++k) {
        int idx = t + k * 256;
        int rr = idx >> 5;
        int cc = idx & (TW - 1);
        float axx = 0.f, axy = 0.f, ayy = 0.f;
#pragma unroll
        for (int i = 0; i < K; ++i) {
            float wi = wc[i];
            axx += wi * hb[0][rr + i][cc];
            axy += wi * hb[1][rr + i][cc];
            ayy += wi * hb[2][rr + i][cc];
        }
        out[b * HW + (h0 + rr) * W + (w0 + cc)] = axy / (sqrtf(axx) * sqrtf(ayy) + EPS);
    }
}

extern "C" void kernel_launch(void* const* d_in, const int* in_sizes, int n_in,
                              void* d_out, int out_size, void* d_ws, size_t ws_size,
                              hipStream_t stream) {
    const float* x     = (const float*)d_in[0];
    const float* y     = (const float*)d_in[1];
    const float* gauss = (const float*)d_in[2];
    float* out = (float*)d_out;

    float* s = (float*)d_ws;        // [3][B][HW]  12 MB

    // K1: B*HW/4 groups / 128 groups-per-block = 2048 blocks (8/CU, 32 waves/CU)
    k_reduce<<<(B * (HW / 4)) / 128, 256, 0, stream>>>(x, y, s);
    // K2: one block per 32x32 output tile: 16*8*8 = 1024 blocks
    k_blur_combine<<<B * (H / TH) * (W / TW), 256, 0, stream>>>(s, gauss, out);
}

// Round 2
// 513.337 us; speedup vs baseline: 1.0500x; 1.0300x over previous
//
#include <hip/hip_runtime.h>
#include <math.h>

// Problem constants (fixed by setup_inputs)
constexpr int B = 16, C = 64, H = 256, W = 256;
constexpr int HW = H * W;            // 65536
constexpr int BHW = B * HW;          // 1048576
constexpr int K = 11, P = 5;         // 11x11 gaussian, pad 5
#define EPS 1e-6f

typedef float v4 __attribute__((ext_vector_type(4)));

// ---------------------------------------------------------------------------
// Kernel 1: channel reduction.  sxx = sum_c x^2, sxy = sum_c x*y, syy = sum_c y^2
// v3: (a) NON-TEMPORAL loads for x/y — 512 MiB of single-use streaming data
// was write-allocating into L2/L3 and thrashing the 256 MiB L3 (round-0
// FETCH showed only 50% of reads reaching HBM at a mere 1.7 TB/s while the
// harness fill sustains 6.6 TB/s).  nt = evict-first hint, still coherent.
// (b) explicit 8-deep rolling register prefetch (fully unrolled -> static
// indices -> stays in VGPRs): guarantees 16 outstanding dwordx4 per wave;
// the previous version's VGPR_Count=36 proves the compiler kept only ~4.
// Grid 1024 blocks (4/CU): occupancy was proven NOT the limiter in round 1.
// ---------------------------------------------------------------------------
__global__ __launch_bounds__(256) void k_reduce(
    const float* __restrict__ x, const float* __restrict__ y,
    float* __restrict__ s /* [3][B][HW] */)
{
    const int GPI = HW / 4;                       // float4 groups per plane = 16384
    int idx = blockIdx.x * 256 + threadIdx.x;     // [0, B*GPI)
    int b = idx >> 14;                            // idx / GPI
    int g = idx & (GPI - 1);

    const v4* x4 = (const v4*)x + (size_t)b * C * GPI + g;
    const v4* y4 = (const v4*)y + (size_t)b * C * GPI + g;

    v4 axx = {0.f, 0.f, 0.f, 0.f};
    v4 axy = axx, ayy = axx;

    v4 bx[8], by[8];
#pragma unroll
    for (int i = 0; i < 8; ++i) {
        bx[i] = __builtin_nontemporal_load(x4 + i * GPI);
        by[i] = __builtin_nontemporal_load(y4 + i * GPI);
    }
#pragma unroll
    for (int c = 0; c < C; ++c) {
        v4 xv = bx[c & 7];
        v4 yv = by[c & 7];
        if (c + 8 < C) {                          // compile-time per unrolled iter
            bx[c & 7] = __builtin_nontemporal_load(x4 + (c + 8) * GPI);
            by[c & 7] = __builtin_nontemporal_load(y4 + (c + 8) * GPI);
        }
        axx += xv * xv;
        axy += xv * yv;
        ayy += yv * yv;
    }

    // s stays in L2/L3 on purpose (consumed by the blur kernel) -> normal stores
    v4* s4 = (v4*)s;
    s4[idx]                 = axx;
    s4[(BHW / 4) + idx]     = axy;
    s4[2 * (BHW / 4) + idx] = ayy;
}

// ---------------------------------------------------------------------------
// Kernel 2: fused separable blur + cosine combine.  The 11x11 gaussian is
// rank-1: g2d[i][j] = (g[5][j]/sqrt(g[5][5])) * (g[i][5]/sqrt(g[5][5])).
// v2: 32x64 tile (was 32x32): halo overhead 1.72x -> 1.52x, and out-writes
// are 256 B contiguous per row.  LDS 70.6 KB -> 2 blocks/CU, grid 512 = 2/CU.
// ---------------------------------------------------------------------------
constexpr int TH = 32, TW = 64;
constexpr int RH = TH + K - 1;   // 42 rows incl. halo
constexpr int RW = TW + K - 1;   // 74 cols incl. halo
constexpr int RWP = RW + 2;      // 76: pad row stride

__global__ __launch_bounds__(256) void k_blur_combine(
    const float* __restrict__ s, const float* __restrict__ gauss,
    float* __restrict__ out /* [B][HW] */)
{
    __shared__ float raw[3][RH][RWP];   // 3*42*76*4 = 38304 B
    __shared__ float hb[3][RH][TW];     // 3*42*64*4 = 32256 B   (total 70560 B)

    int t = threadIdx.x;
    int blk = blockIdx.x;             // B * 8 * 4 = 512
    int b  = blk >> 5;
    int th = (blk >> 2) & 7;
    int tw = blk & 3;
    int h0 = th * TH, w0 = tw * TW;

    // rank-1 weights (broadcast scalar loads, cached)
    float inv = 1.0f / sqrtf(gauss[5 * K + 5]);
    float wr[K], wc[K];
#pragma unroll
    for (int j = 0; j < K; ++j) wr[j] = gauss[5 * K + j] * inv;  // horizontal taps
#pragma unroll
    for (int i = 0; i < K; ++i) wc[i] = gauss[i * K + 5] * inv;  // vertical taps

    // stage raw 42x74 tiles of the 3 maps (zero-padded SAME)
    for (int m = 0; m < 3; ++m) {
        const float* sp = s + m * BHW + b * HW;
        for (int i = t; i < RH * RW; i += 256) {
            int r  = i / RW;
            int c2 = i - r * RW;
            int h = h0 - P + r;
            int w = w0 - P + c2;
            float v = 0.f;
            if (h >= 0 && h < H && w >= 0 && w < W) v = sp[h * W + w];
            raw[m][r][c2] = v;
        }
    }
    __syncthreads();

    // horizontal blur: [3][42][64]
    for (int i = t; i < 3 * RH * TW; i += 256) {
        int m   = i / (RH * TW);
        int rem = i - m * (RH * TW);
        int r  = rem >> 6;           // / TW
        int cc = rem & (TW - 1);
        float a = 0.f;
#pragma unroll
        for (int j = 0; j < K; ++j) a += wr[j] * raw[m][r][cc + j];
        hb[m][r][cc] = a;
    }
    __syncthreads();

    // vertical blur + cosine combine: 32x64 outputs, 8 per thread
#pragma unroll
    for (int k = 0; k < 8; ++k) {
        int idx = t + k * 256;
        int rr = idx >> 6;
        int cc = idx & (TW - 1);
        float axx = 0.f, axy = 0.f, ayy = 0.f;
#pragma unroll
        for (int i = 0; i < K; ++i) {
            float wi = wc[i];
            axx += wi * hb[0][rr + i][cc];
            axy += wi * hb[1][rr + i][cc];
            ayy += wi * hb[2][rr + i][cc];
        }
        out[b * HW + (h0 + rr) * W + (w0 + cc)] = axy / (sqrtf(axx) * sqrtf(ayy) + EPS);
    }
}

extern "C" void kernel_launch(void* const* d_in, const int* in_sizes, int n_in,
                              void* d_out, int out_size, void* d_ws, size_t ws_size,
                              hipStream_t stream) {
    const float* x     = (const float*)d_in[0];
    const float* y     = (const float*)d_in[1];
    const float* gauss = (const float*)d_in[2];
    float* out = (float*)d_out;

    float* s = (float*)d_ws;        // [3][B][HW]  12 MB

    // K1: B*HW/4 float4-groups / 256 threads = 1024 blocks (4/CU)
    k_reduce<<<B * (HW / 4) / 256, 256, 0, stream>>>(x, y, s);
    // K2: one block per 32x64 output tile: 16*8*4 = 512 blocks (2/CU)
    k_blur_combine<<<B * (H / TH) * (W / TW), 256, 0, stream>>>(s, gauss, out);
}

// Round 4
// 505.751 us; speedup vs baseline: 1.0658x; 1.0150x over previous
//
#include <hip/hip_runtime.h>
#include <math.h>

// Problem constants (fixed by setup_inputs)
constexpr int B = 16, C = 64, H = 256, W = 256;
constexpr int HW = H * W;            // 65536
constexpr int BHW = B * HW;          // 1048576
constexpr int K = 11, P = 5;         // 11x11 gaussian, pad 5
#define EPS 1e-6f

typedef float v4 __attribute__((ext_vector_type(4)));

// ---------------------------------------------------------------------------
// Kernel 1: channel reduction.  sxx = sum_c x^2, sxy = sum_c x*y, syy = sum_c y^2
// v4 (re-run; round-3 bench was an infra failure): DRAM-row-locality
// restructure.  Previous versions touched only 4 KiB contiguously per channel
// visit before a 256 KiB plane-stride jump -> one 256 B piece per HBM channel
// per visit -> row-activate on ~every bank access -> stuck at 3.3-3.6 TB/s
// across rounds 0-2 regardless of occupancy (r1 null) or nt hints (r2 +13us).
// Now each block owns a 512-group (8 KiB) span per channel: each thread
// accumulates TWO output float4s (j=0,1 strided by 256 lanes so each
// wave-load instruction stays a fully-coalesced 1 KiB burst), doubling
// sequential locality per stream and halving the number of streams.
// Rolling 4-channel register prefetch (fully unrolled, prologue/main/drain
// split at compile time -> all indices static -> stays in VGPRs) keeps
// 16 x 1 KiB loads in flight per wave.  nt loads kept: 512 MiB of single-use
// data must not thrash the 256 MiB L3.
// ---------------------------------------------------------------------------
constexpr int GPI = HW / 4;          // float4 groups per plane = 16384
constexpr int BPB = 32;              // blocks per batch image
constexpr int GPB = GPI / BPB;       // groups per block = 512 (8 KiB span)

__global__ __launch_bounds__(256) void k_reduce(
    const float* __restrict__ x, const float* __restrict__ y,
    float* __restrict__ s /* [3][B][HW] */)
{
    int blk = blockIdx.x;                     // [0, B*BPB) = 512
    int b  = blk >> 5;
    int g0 = (blk & (BPB - 1)) * GPB;
    int t  = threadIdx.x;

    const v4* x4 = (const v4*)x + (size_t)b * C * GPI + g0 + t;
    const v4* y4 = (const v4*)y + (size_t)b * C * GPI + g0 + t;

    v4 z = {0.f, 0.f, 0.f, 0.f};
    v4 axx0 = z, axy0 = z, ayy0 = z;
    v4 axx1 = z, axy1 = z, ayy1 = z;

    // rolling 4-channel prefetch: [depth][j]
    v4 bx[4][2], by[4][2];
#pragma unroll
    for (int i = 0; i < 4; ++i) {
        bx[i][0] = __builtin_nontemporal_load(x4 + i * GPI);
        bx[i][1] = __builtin_nontemporal_load(x4 + i * GPI + 256);
        by[i][0] = __builtin_nontemporal_load(y4 + i * GPI);
        by[i][1] = __builtin_nontemporal_load(y4 + i * GPI + 256);
    }

    // main: 60 iterations with prefetch of c+4
#pragma unroll
    for (int c = 0; c < C - 4; ++c) {
        v4 xv0 = bx[c & 3][0], xv1 = bx[c & 3][1];
        v4 yv0 = by[c & 3][0], yv1 = by[c & 3][1];
        bx[c & 3][0] = __builtin_nontemporal_load(x4 + (c + 4) * GPI);
        bx[c & 3][1] = __builtin_nontemporal_load(x4 + (c + 4) * GPI + 256);
        by[c & 3][0] = __builtin_nontemporal_load(y4 + (c + 4) * GPI);
        by[c & 3][1] = __builtin_nontemporal_load(y4 + (c + 4) * GPI + 256);
        axx0 += xv0 * xv0; axy0 += xv0 * yv0; ayy0 += yv0 * yv0;
        axx1 += xv1 * xv1; axy1 += xv1 * yv1; ayy1 += yv1 * yv1;
    }
    // drain: last 4 channels, no prefetch
#pragma unroll
    for (int c = C - 4; c < C; ++c) {
        v4 xv0 = bx[c & 3][0], xv1 = bx[c & 3][1];
        v4 yv0 = by[c & 3][0], yv1 = by[c & 3][1];
        axx0 += xv0 * xv0; axy0 += xv0 * yv0; ayy0 += yv0 * yv0;
        axx1 += xv1 * xv1; axy1 += xv1 * yv1; ayy1 += yv1 * yv1;
    }

    // s stays in L2/L3 on purpose (consumed by the blur kernel) -> normal stores
    v4* s4 = (v4*)s;
    int o = b * GPI + g0 + t;
    s4[o]                       = axx0;
    s4[o + 256]                 = axx1;
    s4[(BHW / 4) + o]           = axy0;
    s4[(BHW / 4) + o + 256]     = axy1;
    s4[2 * (BHW / 4) + o]       = ayy0;
    s4[2 * (BHW / 4) + o + 256] = ayy1;
}

// ---------------------------------------------------------------------------
// Kernel 2: fused separable blur + cosine combine.  The 11x11 gaussian is
// rank-1: g2d[i][j] = (g[5][j]/sqrt(g[5][5])) * (g[i][5]/sqrt(g[5][5])).
// 32x64 tile; stage 42x74 halo of the 3 maps in LDS (L2/L3-resident source),
// hblur into LDS, vblur+combine from LDS.  LDS 70.6 KB -> 2 blocks/CU.
// ---------------------------------------------------------------------------
constexpr int TH = 32, TW = 64;
constexpr int RH = TH + K - 1;   // 42 rows incl. halo
constexpr int RW = TW + K - 1;   // 74 cols incl. halo
constexpr int RWP = RW + 2;      // 76: pad row stride

__global__ __launch_bounds__(256) void k_blur_combine(
    const float* __restrict__ s, const float* __restrict__ gauss,
    float* __restrict__ out /* [B][HW] */)
{
    __shared__ float raw[3][RH][RWP];   // 3*42*76*4 = 38304 B
    __shared__ float hb[3][RH][TW];     // 3*42*64*4 = 32256 B   (total 70560 B)

    int t = threadIdx.x;
    int blk = blockIdx.x;             // B * 8 * 4 = 512
    int b  = blk >> 5;
    int th = (blk >> 2) & 7;
    int tw = blk & 3;
    int h0 = th * TH, w0 = tw * TW;

    // rank-1 weights (broadcast scalar loads, cached)
    float inv = 1.0f / sqrtf(gauss[5 * K + 5]);
    float wr[K], wc[K];
#pragma unroll
    for (int j = 0; j < K; ++j) wr[j] = gauss[5 * K + j] * inv;  // horizontal taps
#pragma unroll
    for (int i = 0; i < K; ++i) wc[i] = gauss[i * K + 5] * inv;  // vertical taps

    // stage raw 42x74 tiles of the 3 maps (zero-padded SAME)
    for (int m = 0; m < 3; ++m) {
        const float* sp = s + m * BHW + b * HW;
        for (int i = t; i < RH * RW; i += 256) {
            int r  = i / RW;
            int c2 = i - r * RW;
            int h = h0 - P + r;
            int w = w0 - P + c2;
            float v = 0.f;
            if (h >= 0 && h < H && w >= 0 && w < W) v = sp[h * W + w];
            raw[m][r][c2] = v;
        }
    }
    __syncthreads();

    // horizontal blur: [3][42][64]
    for (int i = t; i < 3 * RH * TW; i += 256) {
        int m   = i / (RH * TW);
        int rem = i - m * (RH * TW);
        int r  = rem >> 6;           // / TW
        int cc = rem & (TW - 1);
        float a = 0.f;
#pragma unroll
        for (int j = 0; j < K; ++j) a += wr[j] * raw[m][r][cc + j];
        hb[m][r][cc] = a;
    }
    __syncthreads();

    // vertical blur + cosine combine: 32x64 outputs, 8 per thread
#pragma unroll
    for (int k = 0; k < 8; ++k) {
        int idx = t + k * 256;
        int rr = idx >> 6;
        int cc = idx & (TW - 1);
        float axx = 0.f, axy = 0.f, ayy = 0.f;
#pragma unroll
        for (int i = 0; i < K; ++i) {
            float wi = wc[i];
            axx += wi * hb[0][rr + i][cc];
            axy += wi * hb[1][rr + i][cc];
            ayy += wi * hb[2][rr + i][cc];
        }
        out[b * HW + (h0 + rr) * W + (w0 + cc)] = axy / (sqrtf(axx) * sqrtf(ayy) + EPS);
    }
}

extern "C" void kernel_launch(void* const* d_in, const int* in_sizes, int n_in,
                              void* d_out, int out_size, void* d_ws, size_t ws_size,
                              hipStream_t stream) {
    const float* x     = (const float*)d_in[0];
    const float* y     = (const float*)d_in[1];
    const float* gauss = (const float*)d_in[2];
    float* out = (float*)d_out;

    float* s = (float*)d_ws;        // [3][B][HW]  12 MB

    // K1: 512 blocks (2/CU), each owns an 8 KiB-per-channel contiguous span
    k_reduce<<<B * BPB, 256, 0, stream>>>(x, y, s);
    // K2: one block per 32x64 output tile: 16*8*4 = 512 blocks (2/CU)
    k_blur_combine<<<B * (H / TH) * (W / TW), 256, 0, stream>>>(s, gauss, out);
}